// Round 1
// baseline (9559.047 us; speedup 1.0000x reference)
//
#include <hip/hip_runtime.h>

// Adaptive softmax NLL (Transformer-XL semantics), fp32 correctness-first version.
// hidden [4096,512] f32, target [4096] i32, weight [50257,512] f32, bias [50257] f32,
// cluster_weight [3,512] f32, cluster_bias [3] f32  ->  out [4096] f32 (nll per token).
//
// Head = weight[:5000] ++ cluster_weight (5003 rows). Routing logit for tail cluster i
// (1-based) is head column 5003-i (TXL "-i" quirk): ci=1 -> cluster row 2, ci=2 -> row 1,
// ci=3 -> row 0.

#define D 512
#define TB 16   // tokens per block

__device__ __forceinline__ void lse_merge(float& m, float& s, float m2, float s2) {
    float M = fmaxf(m, m2);
    s = s * __expf(m - M) + s2 * __expf(m2 - M);
    m = M;
}

__global__ __launch_bounds__(256) void adasoft_nll(
    const float* __restrict__ hidden,
    const int*   __restrict__ target,
    const float* __restrict__ weight,
    const float* __restrict__ bias,
    const float* __restrict__ cweight,
    const float* __restrict__ cbias,
    float* __restrict__ out)
{
    const int tid  = threadIdx.x;
    const int wave = tid >> 6;
    const int lane = tid & 63;
    const int t0g  = blockIdx.x * TB;

    __shared__ int   s_tgt[TB], s_ci[TB], s_idxh[TB];
    __shared__ float s_stash_h[TB];   // head logit at target/routing row
    __shared__ float s_stash_t[TB];   // tail logit at target row
    __shared__ float s_lse[4][TB];    // per-partition logsumexp
    __shared__ float s_red[4][TB][2]; // per-wave (m,s) partials

    if (tid < TB) {
        int tg = target[t0g + tid];
        int ci = (tg >= 5000) + (tg >= 15000) + (tg >= 30000);
        s_tgt[tid]  = tg;
        s_ci[tid]   = ci;
        s_idxh[tid] = ci ? (5003 - ci) : tg;  // virtual head row holding the needed logit
    }
    __syncthreads();

    const int plen_[4]  = {5003, 10000, 15000, 20257};
    const int pbase_[4] = {0, 5000, 15000, 30000};

    // Wave-uniform hidden pointer: all lanes read the same address -> scalar loads.
    const float4* hp = (const float4*)(hidden + (size_t)t0g * D);

    for (int p = 0; p < 4; ++p) {
        const int plen  = plen_[p];
        const int pbase = pbase_[p];

        float rm[TB], rs[TB];
        #pragma unroll
        for (int t = 0; t < TB; ++t) { rm[t] = -1e30f; rs[t] = 0.f; }

        for (int tile = 0; tile < plen; tile += 1024) {
            int vr[4]; bool valid[4]; const float4* wp[4]; float bb[4];
            #pragma unroll
            for (int j = 0; j < 4; ++j) {
                vr[j]    = tile + tid + j * 256;      // lanes -> consecutive rows
                valid[j] = vr[j] < plen;
                int v = valid[j] ? vr[j] : 0;
                if (p == 0 && v >= 5000) {            // cluster routing rows
                    wp[j] = (const float4*)(cweight + (size_t)(v - 5000) * D);
                    bb[j] = cbias[v - 5000];
                } else {
                    int r = pbase + v;
                    wp[j] = (const float4*)(weight + (size_t)r * D);
                    bb[j] = bias[r];
                }
            }

            float acc[4][TB];
            #pragma unroll
            for (int j = 0; j < 4; ++j)
                #pragma unroll
                for (int t = 0; t < TB; ++t) acc[j][t] = 0.f;

            #pragma unroll 2
            for (int dq = 0; dq < D / 4; ++dq) {
                float4 w[4];
                #pragma unroll
                for (int j = 0; j < 4; ++j) w[j] = wp[j][dq];
                #pragma unroll
                for (int t = 0; t < TB; ++t) {
                    float4 h4 = hp[t * (D / 4) + dq];   // uniform across lanes
                    #pragma unroll
                    for (int j = 0; j < 4; ++j) {
                        acc[j][t] = fmaf(w[j].x, h4.x, acc[j][t]);
                        acc[j][t] = fmaf(w[j].y, h4.y, acc[j][t]);
                        acc[j][t] = fmaf(w[j].z, h4.z, acc[j][t]);
                        acc[j][t] = fmaf(w[j].w, h4.w, acc[j][t]);
                    }
                }
            }

            // Epilogue: bias, stash specific logits, online LSE update.
            #pragma unroll
            for (int j = 0; j < 4; ++j) {
                if (!valid[j]) continue;
                #pragma unroll
                for (int t = 0; t < TB; ++t) {
                    float logit = acc[j][t] + bb[j];
                    if (p == 0) {
                        if (vr[j] == s_idxh[t]) s_stash_h[t] = logit;
                    } else {
                        if (s_ci[t] == p && pbase + vr[j] == s_tgt[t]) s_stash_t[t] = logit;
                    }
                    float M = fmaxf(rm[t], logit);
                    rs[t] = rs[t] * __expf(rm[t] - M) + __expf(logit - M);
                    rm[t] = M;
                }
            }
        }

        // Wave butterfly reduce (all lanes converge to same (m,s)).
        #pragma unroll
        for (int t = 0; t < TB; ++t) {
            #pragma unroll
            for (int off = 32; off > 0; off >>= 1) {
                float m2 = __shfl_xor(rm[t], off, 64);
                float s2 = __shfl_xor(rs[t], off, 64);
                lse_merge(rm[t], rs[t], m2, s2);
            }
        }
        if (lane == 0) {
            #pragma unroll
            for (int t = 0; t < TB; ++t) { s_red[wave][t][0] = rm[t]; s_red[wave][t][1] = rs[t]; }
        }
        __syncthreads();
        if (tid < TB) {
            float m = s_red[0][tid][0], s = s_red[0][tid][1];
            lse_merge(m, s, s_red[1][tid][0], s_red[1][tid][1]);
            lse_merge(m, s, s_red[2][tid][0], s_red[2][tid][1]);
            lse_merge(m, s, s_red[3][tid][0], s_red[3][tid][1]);
            s_lse[p][tid] = m + __logf(s);
        }
        __syncthreads();
    }

    if (tid < TB) {
        int ci = s_ci[tid];
        float nll = s_lse[0][tid] - s_stash_h[tid];
        if (ci) nll += s_lse[ci][tid] - s_stash_t[tid];
        out[t0g + tid] = nll;
    }
}

extern "C" void kernel_launch(void* const* d_in, const int* in_sizes, int n_in,
                              void* d_out, int out_size, void* d_ws, size_t ws_size,
                              hipStream_t stream) {
    const float* hidden  = (const float*)d_in[0];
    const int*   targetp = (const int*)d_in[1];
    const float* weight  = (const float*)d_in[2];
    const float* biasp   = (const float*)d_in[3];
    const float* cweight = (const float*)d_in[4];
    const float* cbias   = (const float*)d_in[5];
    float* outp = (float*)d_out;

    const int n = in_sizes[1];          // 4096 tokens (divisible by TB=16)
    const int nblocks = n / TB;

    adasoft_nll<<<nblocks, 256, 0, stream>>>(hidden, targetp, weight, biasp,
                                             cweight, cbias, outp);
}

// Round 2
// 928.727 us; speedup vs baseline: 10.2926x; 10.2926x over previous
//
#include <hip/hip_runtime.h>

// Adaptive softmax NLL — two-stage bf16-MFMA version.
// Partitioned reordered weight matrix (padded to 128-row chunks):
//   p0 head : rows [0,5120)   = weight[0:5000] ++ cluster_weight[0:3] ++ pad   (5003 real)
//   p1 tail1: rows [5120,15232)  = weight[5000:15000]  ++ pad                  (10000 real)
//   p2 tail2: rows [15232,30336) = weight[15000:30000] ++ pad                  (15000 real)
//   p3 tail3: rows [30336,50688) = weight[30000:50257] ++ pad                  (20257 real)
// Pad rows: w=0, bias=-1e30 (vanish in LSE).
// Chunks of 128 rows: head 40, t1 79, t2 118, t3 159 -> 396 total.

#define D 512
#define NROWS_PAD 50688
#define NCHUNK 396
#define NTOK 4096

typedef __attribute__((ext_vector_type(8))) short short8;
typedef __attribute__((ext_vector_type(4))) float f32x4;

__device__ __forceinline__ unsigned short f2bf(float f) {
    unsigned int u = __float_as_uint(f);
    u += 0x7FFFu + ((u >> 16) & 1u);
    return (unsigned short)(u >> 16);
}

// ---------------- convert / reorder / pad ----------------
__global__ __launch_bounds__(128) void k_convert(
    const float* __restrict__ weight, const float* __restrict__ bias,
    const float* __restrict__ cweight, const float* __restrict__ cbias,
    const float* __restrict__ hidden,
    unsigned short* __restrict__ wsW, float* __restrict__ wsB,
    unsigned short* __restrict__ wsH)
{
    const int r = blockIdx.x;
    const int i = threadIdx.x;   // 0..127, 4 floats each
    if (r < NROWS_PAD) {
        const int pstart[4] = {0, 5120, 15232, 30336};
        const int plen[4]   = {5003, 10000, 15000, 20257};
        const int psrc[4]   = {0, 5000, 15000, 30000};
        int p = (r < 5120) ? 0 : (r < 15232) ? 1 : (r < 30336) ? 2 : 3;
        int o = r - pstart[p];
        const float* src = nullptr;
        float b = -1e30f;
        if (o < plen[p]) {
            if (p == 0 && o >= 5000) { src = cweight + (size_t)(o - 5000) * D; b = cbias[o - 5000]; }
            else { int sr = psrc[p] + o; src = weight + (size_t)sr * D; b = bias[sr]; }
        }
        float4 v = src ? ((const float4*)src)[i] : make_float4(0.f, 0.f, 0.f, 0.f);
        ushort4 u;
        u.x = f2bf(v.x); u.y = f2bf(v.y); u.z = f2bf(v.z); u.w = f2bf(v.w);
        ((ushort4*)(wsW + (size_t)r * D))[i] = u;
        if (i == 0) wsB[r] = b;
    } else {
        int hr = r - NROWS_PAD;
        float4 v = ((const float4*)(hidden + (size_t)hr * D))[i];
        ushort4 u;
        u.x = f2bf(v.x); u.y = f2bf(v.y); u.z = f2bf(v.z); u.w = f2bf(v.w);
        ((ushort4*)(wsH + (size_t)hr * D))[i] = u;
    }
}

// ---------------- exact fp32 dots for the two needed logits ----------------
__global__ __launch_bounds__(256) void k_stash(
    const float* __restrict__ hidden, const int* __restrict__ target,
    const float* __restrict__ weight, const float* __restrict__ bias,
    const float* __restrict__ cweight, const float* __restrict__ cbias,
    float2* __restrict__ stash)
{
    const int wave = threadIdx.x >> 6, lane = threadIdx.x & 63;
    const int t = blockIdx.x * 4 + wave;
    const int tg = target[t];
    const int ci = (tg >= 5000) + (tg >= 15000) + (tg >= 30000);
    const float4* h = (const float4*)(hidden + (size_t)t * D);
    const float4* w = (const float4*)(weight + (size_t)tg * D);
    const float4* c = (const float4*)(cweight + (size_t)(ci ? 3 - ci : 0) * D);
    float dw = 0.f, dc = 0.f;
    #pragma unroll
    for (int u = 0; u < 2; ++u) {
        float4 hh = h[lane * 2 + u];
        float4 ww = w[lane * 2 + u];
        float4 cc = c[lane * 2 + u];
        dw += hh.x * ww.x + hh.y * ww.y + hh.z * ww.z + hh.w * ww.w;
        dc += hh.x * cc.x + hh.y * cc.y + hh.z * cc.z + hh.w * cc.w;
    }
    #pragma unroll
    for (int off = 1; off < 64; off <<= 1) {
        dw += __shfl_xor(dw, off, 64);
        dc += __shfl_xor(dc, off, 64);
    }
    if (lane == 0) {
        float head = ci ? dc + cbias[3 - ci] : dw + bias[tg];
        float tail = ci ? dw + bias[tg]      : 0.f;
        stash[t] = make_float2(head, tail);
    }
}

// ---------------- stage A: per-(token, 128-row chunk) partial LSE ----------------
__global__ __launch_bounds__(256) void k_stageA(
    const unsigned short* __restrict__ wsW, const float* __restrict__ wsB,
    const unsigned short* __restrict__ wsH, float2* __restrict__ partials)
{
    const int chunk = blockIdx.x;           // 0..395
    const int ttile = blockIdx.y;           // 0..31
    const int tid = threadIdx.x, wave = tid >> 6, lane = tid & 63;
    const int r = lane & 15, kg = lane >> 4;
    const int row0 = chunk * 128;
    const int tokW = ttile * 128 + wave * 32;   // this wave's 32 tokens

    const short8* Wp[8];
    const short8* Hp[2];
    #pragma unroll
    for (int rt = 0; rt < 8; ++rt)
        Wp[rt] = (const short8*)(wsW + (size_t)(row0 + rt * 16 + r) * D + kg * 8);
    #pragma unroll
    for (int tt = 0; tt < 2; ++tt)
        Hp[tt] = (const short8*)(wsH + (size_t)(tokW + tt * 16 + r) * D + kg * 8);

    f32x4 acc[2][8];
    #pragma unroll
    for (int tt = 0; tt < 2; ++tt)
        #pragma unroll
        for (int rt = 0; rt < 8; ++rt)
            acc[tt][rt] = (f32x4){0.f, 0.f, 0.f, 0.f};

    #pragma unroll 4
    for (int ks = 0; ks < 16; ++ks) {      // K = 512, 32 per step; short8 stride 4
        short8 bfr[2], afr[8];
        #pragma unroll
        for (int tt = 0; tt < 2; ++tt) bfr[tt] = Hp[tt][ks * 4];
        #pragma unroll
        for (int rt = 0; rt < 8; ++rt) afr[rt] = Wp[rt][ks * 4];
        #pragma unroll
        for (int tt = 0; tt < 2; ++tt)
            #pragma unroll
            for (int rt = 0; rt < 8; ++rt)
                acc[tt][rt] = __builtin_amdgcn_mfma_f32_16x16x32_bf16(
                    afr[rt], bfr[tt], acc[tt][rt], 0, 0, 0);
    }

    // bias add: D layout col=lane&15 (token), row = rt*16 + kg*4 + j
    f32x4 bb[8];
    #pragma unroll
    for (int rt = 0; rt < 8; ++rt)
        bb[rt] = *(const f32x4*)(wsB + row0 + rt * 16 + kg * 4);

    #pragma unroll
    for (int tt = 0; tt < 2; ++tt) {
        float m = -1e30f;
        #pragma unroll
        for (int rt = 0; rt < 8; ++rt)
            #pragma unroll
            for (int j = 0; j < 4; ++j) {
                acc[tt][rt][j] += bb[rt][j];
                m = fmaxf(m, acc[tt][rt][j]);
            }
        float s = 0.f;
        #pragma unroll
        for (int rt = 0; rt < 8; ++rt)
            #pragma unroll
            for (int j = 0; j < 4; ++j)
                s += __expf(acc[tt][rt][j] - m);
        // butterfly across the 4 lane-groups holding different rows (same token)
        #pragma unroll
        for (int off = 16; off < 64; off <<= 1) {
            float m2 = __shfl_xor(m, off, 64);
            float s2 = __shfl_xor(s, off, 64);
            float M = fmaxf(m, m2);
            s = s * __expf(m - M) + s2 * __expf(m2 - M);
            m = M;
        }
        if (kg == 0)
            partials[(size_t)(tokW + tt * 16 + r) * NCHUNK + chunk] = make_float2(m, s);
    }
}

// ---------------- stage B: merge chunks -> nll ----------------
__global__ __launch_bounds__(256) void k_stageB(
    const float2* __restrict__ partials, const float2* __restrict__ stash,
    const int* __restrict__ target, float* __restrict__ out)
{
    const int wave = threadIdx.x >> 6, lane = threadIdx.x & 63;
    const int t = blockIdx.x * 4 + wave;
    const int tg = target[t];
    const int ci = (tg >= 5000) + (tg >= 15000) + (tg >= 30000);
    const float2* P = partials + (size_t)t * NCHUNK;

    // head: chunks [0,40)
    float m = -1e30f, s = 0.f;
    if (lane < 40) { float2 p = P[lane]; m = p.x; s = p.y; }
    #pragma unroll
    for (int off = 1; off < 64; off <<= 1) {
        float m2 = __shfl_xor(m, off, 64);
        float s2 = __shfl_xor(s, off, 64);
        float M = fmaxf(m, m2);
        s = s * __expf(m - M) + s2 * __expf(m2 - M);
        m = M;
    }
    float2 st = stash[t];
    float nll = (m + __logf(s)) - st.x;

    if (ci) {
        const int cb[4] = {0, 40, 119, 237};
        const int cl[4] = {0, 79, 118, 159};
        float m2 = -1e30f, s2 = 0.f;
        for (int c = lane; c < cl[ci]; c += 64) {
            float2 p = P[cb[ci] + c];
            float M = fmaxf(m2, p.x);
            s2 = s2 * __expf(m2 - M) + p.y * __expf(p.x - M);
            m2 = M;
        }
        #pragma unroll
        for (int off = 1; off < 64; off <<= 1) {
            float mm = __shfl_xor(m2, off, 64);
            float ss = __shfl_xor(s2, off, 64);
            float M = fmaxf(m2, mm);
            s2 = s2 * __expf(m2 - M) + ss * __expf(mm - M);
            m2 = M;
        }
        nll += (m2 + __logf(s2)) - st.y;
    }
    if (lane == 0) out[t] = nll;
}

extern "C" void kernel_launch(void* const* d_in, const int* in_sizes, int n_in,
                              void* d_out, int out_size, void* d_ws, size_t ws_size,
                              hipStream_t stream) {
    const float* hidden  = (const float*)d_in[0];
    const int*   targetp = (const int*)d_in[1];
    const float* weight  = (const float*)d_in[2];
    const float* biasp   = (const float*)d_in[3];
    const float* cweight = (const float*)d_in[4];
    const float* cbias   = (const float*)d_in[5];
    float* outp = (float*)d_out;

    char* ws = (char*)d_ws;
    unsigned short* wsW = (unsigned short*)(ws);                       // 51,904,512 B
    float*          wsB = (float*)(ws + 51904512);                     //    202,752 B
    unsigned short* wsH = (unsigned short*)(ws + 52107264);            //  4,194,304 B
    float2*         wsP = (float2*)(ws + 56301568);                    // 12,976,128 B
    float2*         wsS = (float2*)(ws + 69277696);                    //     32,768 B

    k_convert<<<NROWS_PAD + NTOK, 128, 0, stream>>>(weight, biasp, cweight, cbias,
                                                    hidden, wsW, wsB, wsH);
    k_stash<<<NTOK / 4, 256, 0, stream>>>(hidden, targetp, weight, biasp,
                                          cweight, cbias, wsS);
    k_stageA<<<dim3(NCHUNK, 32), 256, 0, stream>>>(wsW, wsB, wsH, wsP);
    k_stageB<<<NTOK / 4, 256, 0, stream>>>(wsP, wsS, targetp, outp);
}

// Round 3
// 212.528 us; speedup vs baseline: 44.9778x; 4.3699x over previous
//
#include <hip/hip_runtime.h>

// Adaptive softmax NLL — bucketed bf16-MFMA version with LDS-staged GEMM.
//
// Padded reordered weight (bf16) in ws:
//   head : rows [0,5120)      = weight[0:5000] ++ cluster_weight ++ pad (5003 real, 40 chunks)
//   tail1: rows [5120,15232)  = weight[5000:15000]  ++ pad (79 chunks)
//   tail2: rows [15232,30336) = weight[15000:30000] ++ pad (118 chunks)
//   tail3: rows [30336,50688) = weight[30000:50257] ++ pad (159 chunks)
// Pad rows: w=0, bias=-1e30 (vanish in LSE merges).
// Tokens bucketed by cluster; tail GEMMs run only (cluster rows) x (cluster tokens).

#define D 512
#define NROWS_PAD 50688
#define NTOK 4096
#define NTOKP 4736          // 4096 + 3*128 max bucket padding
#define HEAD_CHUNKS 40
#define TAILP_STRIDE 160

typedef __attribute__((ext_vector_type(8))) short short8;
typedef __attribute__((ext_vector_type(4))) float f32x4;

__device__ __forceinline__ unsigned short f2bf(float f) {
    unsigned int u = __float_as_uint(f);
    u += 0x7FFFu + ((u >> 16) & 1u);
    return (unsigned short)(u >> 16);
}

__device__ __forceinline__ void gload_lds16(const void* g, void* l) {
    __builtin_amdgcn_global_load_lds(
        (const __attribute__((address_space(1))) unsigned int*)g,
        (__attribute__((address_space(3))) unsigned int*)l, 16, 0, 0);
}

// ---------------- bucket tokens by cluster (deterministic counting sort) ----------------
__global__ __launch_bounds__(256) void k_bucket(
    const int* __restrict__ target, int* __restrict__ perm,
    int* __restrict__ inv, int* __restrict__ meta)
{
    __shared__ int cnt[256][4];
    __shared__ int basesh[256][4];
    __shared__ int sTot[4], sOff[4];
    const int th = threadIdx.x;
    for (int p = th; p < NTOKP; p += 256) perm[p] = -1;
    int lc[4] = {0, 0, 0, 0};
    #pragma unroll
    for (int i = 0; i < 16; ++i) {
        int tg = target[th * 16 + i];
        int c = (tg >= 5000) + (tg >= 15000) + (tg >= 30000);
        lc[c]++;
    }
    #pragma unroll
    for (int c = 0; c < 4; ++c) cnt[th][c] = lc[c];
    __syncthreads();
    if (th < 4) {
        int tot = 0;
        for (int i = 0; i < 256; ++i) tot += cnt[i][th];
        sTot[th] = tot;
    }
    __syncthreads();
    if (th == 0) {
        int b = 0;
        for (int c = 1; c < 4; ++c) { sOff[c] = b; b += ((sTot[c] + 127) >> 7) << 7; }
        meta[0] = sTot[1]; meta[1] = sTot[2]; meta[2] = sTot[3];
        meta[3] = sOff[1]; meta[4] = sOff[2]; meta[5] = sOff[3];
        meta[6] = (sTot[1] + 127) >> 7;
        meta[7] = (sTot[2] + 127) >> 7;
        meta[8] = (sTot[3] + 127) >> 7;
    }
    __syncthreads();
    if (th >= 1 && th < 4) {
        int run = sOff[th];
        for (int i = 0; i < 256; ++i) { basesh[i][th] = run; run += cnt[i][th]; }
    }
    __syncthreads();
    int run[4];
    #pragma unroll
    for (int c = 1; c < 4; ++c) run[c] = basesh[th][c];
    for (int i = 0; i < 16; ++i) {
        int t = th * 16 + i;
        int tg = target[t];
        int c = (tg >= 5000) + (tg >= 15000) + (tg >= 30000);
        if (c > 0) { int pos = run[c]++; perm[pos] = t; inv[t] = pos; }
        else inv[t] = -1;
    }
}

// ---------------- convert / reorder / pad / gather ----------------
__global__ __launch_bounds__(128) void k_convert(
    const float* __restrict__ weight, const float* __restrict__ bias,
    const float* __restrict__ cweight, const float* __restrict__ cbias,
    const float* __restrict__ hidden, const int* __restrict__ perm,
    unsigned short* __restrict__ wsW, float* __restrict__ wsB,
    unsigned short* __restrict__ wsH, unsigned short* __restrict__ wsHc)
{
    const int r = blockIdx.x;
    const int i = threadIdx.x;   // 0..127, one float4 each
    if (r < NROWS_PAD) {
        const int pstart[4] = {0, 5120, 15232, 30336};
        const int plen[4]   = {5003, 10000, 15000, 20257};
        const int psrc[4]   = {0, 5000, 15000, 30000};
        int p = (r < 5120) ? 0 : (r < 15232) ? 1 : (r < 30336) ? 2 : 3;
        int o = r - pstart[p];
        const float* src = nullptr;
        float b = -1e30f;
        if (o < plen[p]) {
            if (p == 0 && o >= 5000) { src = cweight + (size_t)(o - 5000) * D; b = cbias[o - 5000]; }
            else { int sr = psrc[p] + o; src = weight + (size_t)sr * D; b = bias[sr]; }
        }
        float4 v = src ? ((const float4*)src)[i] : make_float4(0.f, 0.f, 0.f, 0.f);
        ushort4 u;
        u.x = f2bf(v.x); u.y = f2bf(v.y); u.z = f2bf(v.z); u.w = f2bf(v.w);
        ((ushort4*)(wsW + (size_t)r * D))[i] = u;
        if (i == 0) wsB[r] = b;
    } else if (r < NROWS_PAD + NTOK) {
        int hr = r - NROWS_PAD;
        float4 v = ((const float4*)(hidden + (size_t)hr * D))[i];
        ushort4 u;
        u.x = f2bf(v.x); u.y = f2bf(v.y); u.z = f2bf(v.z); u.w = f2bf(v.w);
        ((ushort4*)(wsH + (size_t)hr * D))[i] = u;
    } else {
        int p = r - NROWS_PAD - NTOK;       // compacted position
        int tok = perm[p];
        float4 v = (tok >= 0) ? ((const float4*)(hidden + (size_t)tok * D))[i]
                              : make_float4(0.f, 0.f, 0.f, 0.f);
        ushort4 u;
        u.x = f2bf(v.x); u.y = f2bf(v.y); u.z = f2bf(v.z); u.w = f2bf(v.w);
        ((ushort4*)(wsHc + (size_t)p * D))[i] = u;
    }
}

// ---------------- exact fp32 dots for the two needed logits ----------------
__global__ __launch_bounds__(256) void k_stash(
    const float* __restrict__ hidden, const int* __restrict__ target,
    const float* __restrict__ weight, const float* __restrict__ bias,
    const float* __restrict__ cweight, const float* __restrict__ cbias,
    float2* __restrict__ stash)
{
    const int wave = threadIdx.x >> 6, lane = threadIdx.x & 63;
    const int t = blockIdx.x * 4 + wave;
    const int tg = target[t];
    const int ci = (tg >= 5000) + (tg >= 15000) + (tg >= 30000);
    const float4* h = (const float4*)(hidden + (size_t)t * D);
    const float4* w = (const float4*)(weight + (size_t)tg * D);
    const float4* c = (const float4*)(cweight + (size_t)(ci ? 3 - ci : 0) * D);
    float dw = 0.f, dc = 0.f;
    #pragma unroll
    for (int u = 0; u < 2; ++u) {
        float4 hh = h[lane * 2 + u];
        float4 ww = w[lane * 2 + u];
        float4 cc = c[lane * 2 + u];
        dw += hh.x * ww.x + hh.y * ww.y + hh.z * ww.z + hh.w * ww.w;
        dc += hh.x * cc.x + hh.y * cc.y + hh.z * cc.z + hh.w * cc.w;
    }
    #pragma unroll
    for (int off = 1; off < 64; off <<= 1) {
        dw += __shfl_xor(dw, off, 64);
        dc += __shfl_xor(dc, off, 64);
    }
    if (lane == 0) {
        float head = ci ? dc + cbias[3 - ci] : dw + bias[tg];
        float tail = ci ? dw + bias[tg]      : 0.f;
        stash[t] = make_float2(head, tail);
    }
}

// ---------------- LDS-staged 128x128 GEMM + per-chunk LSE partial ----------------
// blockIdx.x = row chunk, blockIdx.y = token tile. 256 threads = 4 waves (2x2).
// Double-buffered LDS, global_load_lds width 16, T2 XOR-swizzle via pre-swizzled source.
__global__ __launch_bounds__(256) void k_gemm(
    const unsigned short* __restrict__ W,    // row base already applied
    const float* __restrict__ Bias,          // row base already applied
    const unsigned short* __restrict__ H,    // token matrix base
    float2* __restrict__ P, int pstride,
    const int* __restrict__ basePtr,         // nullptr -> 0
    const int* __restrict__ ntilePtr)        // nullptr -> all tiles
{
    const int chunk = blockIdx.x, tile = blockIdx.y;
    if (ntilePtr && tile >= *ntilePtr) return;
    const int tokBase = basePtr ? *basePtr : 0;

    const int tid = threadIdx.x;
    const int w = tid >> 6, lane = tid & 63;
    const int wm = w >> 1, wn = w & 1;

    __shared__ unsigned short ldsA[2][128 * 64];
    __shared__ unsigned short ldsB[2][128 * 64];
    __shared__ float2 sred[2][128];

    const unsigned short* Wb = W + (size_t)chunk * 128 * D;
    const unsigned short* Hb = H + (size_t)(tokBase + tile * 128) * D;

    f32x4 acc[4][4];
    #pragma unroll
    for (int m = 0; m < 4; ++m)
        #pragma unroll
        for (int n = 0; n < 4; ++n) acc[m][n] = (f32x4){0.f, 0.f, 0.f, 0.f};

    const int eBase = w * 256 + lane;

    auto STAGE = [&](int buf, int t) {
        #pragma unroll
        for (int j = 0; j < 4; ++j) {
            int e = eBase + j * 64;
            int r = e >> 3;
            int ck = (e & 7) ^ (r & 7);                 // inverse-swizzled source chunk
            size_t go = (size_t)r * D + (size_t)t * 64 + ck * 8;
            gload_lds16(Wb + go, &ldsA[buf][(w * 4 + j) * 512]);
            gload_lds16(Hb + go, &ldsB[buf][(w * 4 + j) * 512]);
        }
    };

    STAGE(0, 0);
    __syncthreads();

    const int xorv = (lane & 7) << 4;          // byte XOR for swizzled read
    const int rowA = wm * 64 + (lane & 15);
    const int rowB = wn * 64 + (lane & 15);
    const int kbase = (lane >> 4) * 16;        // byte offset within 32-k step

    int buf = 0;
    for (int t = 0; t < 8; ++t) {
        if (t < 7) STAGE(buf ^ 1, t + 1);
        #pragma unroll
        for (int ks = 0; ks < 2; ++ks) {
            const int koff = (ks * 64 + kbase) ^ xorv;
            short8 af[4], bfr[4];
            #pragma unroll
            for (int m = 0; m < 4; ++m)
                af[m] = *(const short8*)((const char*)&ldsA[buf][0] + (rowA + m * 16) * 128 + koff);
            #pragma unroll
            for (int n = 0; n < 4; ++n)
                bfr[n] = *(const short8*)((const char*)&ldsB[buf][0] + (rowB + n * 16) * 128 + koff);
            #pragma unroll
            for (int m = 0; m < 4; ++m)
                #pragma unroll
                for (int n = 0; n < 4; ++n)
                    acc[m][n] = __builtin_amdgcn_mfma_f32_16x16x32_bf16(af[m], bfr[n], acc[m][n], 0, 0, 0);
        }
        __syncthreads();
        buf ^= 1;
    }

    // epilogue: bias + per-token LSE over this chunk's 128 rows
    const int rg = lane >> 4;
    f32x4 bb[4];
    #pragma unroll
    for (int m = 0; m < 4; ++m)
        bb[m] = *(const f32x4*)(Bias + chunk * 128 + wm * 64 + m * 16 + rg * 4);

    #pragma unroll
    for (int n = 0; n < 4; ++n) {
        float mval = -1e30f;
        #pragma unroll
        for (int m = 0; m < 4; ++m)
            #pragma unroll
            for (int j = 0; j < 4; ++j) {
                acc[m][n][j] += bb[m][j];
                mval = fmaxf(mval, acc[m][n][j]);
            }
        float sval = 0.f;
        #pragma unroll
        for (int m = 0; m < 4; ++m)
            #pragma unroll
            for (int j = 0; j < 4; ++j)
                sval += __expf(acc[m][n][j] - mval);
        #pragma unroll
        for (int off = 16; off < 64; off <<= 1) {
            float m2 = __shfl_xor(mval, off, 64);
            float s2 = __shfl_xor(sval, off, 64);
            float M = fmaxf(mval, m2);
            sval = sval * __expf(mval - M) + s2 * __expf(m2 - M);
            mval = M;
        }
        if (lane < 16)
            sred[wm][wn * 64 + n * 16 + lane] = make_float2(mval, sval);
    }
    __syncthreads();
    if (tid < 128) {
        float2 p0 = sred[0][tid], p1 = sred[1][tid];
        float M = fmaxf(p0.x, p1.x);
        float S = p0.y * __expf(p0.x - M) + p1.y * __expf(p1.x - M);
        P[(size_t)(tokBase + tile * 128 + tid) * pstride + chunk] = make_float2(M, S);
    }
}

// ---------------- merge partials -> nll ----------------
__global__ __launch_bounds__(256) void k_stageB(
    const float2* __restrict__ headP, const float2* __restrict__ tailP,
    const float2* __restrict__ stash, const int* __restrict__ target,
    const int* __restrict__ inv, float* __restrict__ out)
{
    const int wave = threadIdx.x >> 6, lane = threadIdx.x & 63;
    const int t = blockIdx.x * 4 + wave;
    const int tg = target[t];
    const int ci = (tg >= 5000) + (tg >= 15000) + (tg >= 30000);

    float m = -1e30f, s = 0.f;
    if (lane < HEAD_CHUNKS) { float2 p = headP[(size_t)t * HEAD_CHUNKS + lane]; m = p.x; s = p.y; }
    #pragma unroll
    for (int off = 1; off < 64; off <<= 1) {
        float m2 = __shfl_xor(m, off, 64);
        float s2 = __shfl_xor(s, off, 64);
        float M = fmaxf(m, m2);
        s = s * __expf(m - M) + s2 * __expf(m2 - M);
        m = M;
    }
    float2 st = stash[t];
    float nll = (m + __logf(s)) - st.x;

    if (ci) {
        const int nch_[4] = {0, 79, 118, 159};
        const int nch = nch_[ci];
        const int pos = inv[t];
        float m2 = -1e30f, s2 = 0.f;
        for (int c = lane; c < nch; c += 64) {
            float2 p = tailP[(size_t)pos * TAILP_STRIDE + c];
            float M = fmaxf(m2, p.x);
            s2 = s2 * __expf(m2 - M) + p.y * __expf(p.x - M);
            m2 = M;
        }
        #pragma unroll
        for (int off = 1; off < 64; off <<= 1) {
            float mm = __shfl_xor(m2, off, 64);
            float ss = __shfl_xor(s2, off, 64);
            float M = fmaxf(m2, mm);
            s2 = s2 * __expf(m2 - M) + ss * __expf(mm - M);
            m2 = M;
        }
        nll += (m2 + __logf(s2)) - st.y;
    }
    if (lane == 0) out[t] = nll;
}

extern "C" void kernel_launch(void* const* d_in, const int* in_sizes, int n_in,
                              void* d_out, int out_size, void* d_ws, size_t ws_size,
                              hipStream_t stream) {
    const float* hidden  = (const float*)d_in[0];
    const int*   targetp = (const int*)d_in[1];
    const float* weight  = (const float*)d_in[2];
    const float* biasp   = (const float*)d_in[3];
    const float* cweight = (const float*)d_in[4];
    const float* cbias   = (const float*)d_in[5];
    float* outp = (float*)d_out;

    char* ws = (char*)d_ws;
    unsigned short* wsW   = (unsigned short*)(ws);                 // 51,904,512 B
    float*          wsB   = (float*)(ws + 51904512);               //    202,752 B
    unsigned short* wsH   = (unsigned short*)(ws + 52107264);      //  4,194,304 B
    unsigned short* wsHc  = (unsigned short*)(ws + 56301568);      //  4,849,664 B
    float2*         headP = (float2*)(ws + 61151232);              //  1,310,720 B
    float2*         tailP = (float2*)(ws + 62461952);              //  6,062,080 B
    float2*         wsS   = (float2*)(ws + 68524032);              //     32,768 B
    int*            perm  = (int*)(ws + 68556800);                 //     18,944 B
    int*            inv   = (int*)(ws + 68575744);                 //     16,384 B
    int*            meta  = (int*)(ws + 68592128);                 //         64 B

    k_bucket<<<1, 256, 0, stream>>>(targetp, perm, inv, meta);
    k_convert<<<NROWS_PAD + NTOK + NTOKP, 128, 0, stream>>>(
        weight, biasp, cweight, cbias, hidden, perm, wsW, wsB, wsH, wsHc);
    k_stash<<<NTOK / 4, 256, 0, stream>>>(hidden, targetp, weight, biasp,
                                          cweight, cbias, wsS);
    // head: all tokens x 40 chunks
    k_gemm<<<dim3(HEAD_CHUNKS, 32), 256, 0, stream>>>(
        wsW, wsB, wsH, headP, HEAD_CHUNKS, nullptr, nullptr);
    // tails: bucketed tokens x cluster chunks (worst-case grid, early-exit on ntile)
    k_gemm<<<dim3(79, 32), 256, 0, stream>>>(
        wsW + (size_t)5120 * D,  wsB + 5120,  wsHc, tailP, TAILP_STRIDE, meta + 3, meta + 6);
    k_gemm<<<dim3(118, 32), 256, 0, stream>>>(
        wsW + (size_t)15232 * D, wsB + 15232, wsHc, tailP, TAILP_STRIDE, meta + 4, meta + 7);
    k_gemm<<<dim3(159, 32), 256, 0, stream>>>(
        wsW + (size_t)30336 * D, wsB + 30336, wsHc, tailP, TAILP_STRIDE, meta + 5, meta + 8);
    k_stageB<<<NTOK / 4, 256, 0, stream>>>(headP, tailP, wsS, targetp, inv, outp);
}